// Round 2
// baseline (2302.038 us; speedup 1.0000x reference)
//
#include <hip/hip_runtime.h>

typedef unsigned short u16;
typedef unsigned int u32;

// d_ws layout (floats): six transposed 64x64 matrices + s_ion
#define OFF_Wsa1T  0
#define OFF_Wdi1T  4096
#define OFF_Wei1T  8192
#define OFF_WeeiT  12288
#define OFF_We0T   16384
#define OFF_We1T   20480
#define OFF_SION   24576
// total 24832 floats

// d_out layout (float elements):
#define OUT_EMB 0
#define OUT_ION 4194304
#define OUT_EE  4194432
#define OUT_EI  37748864

__device__ __forceinline__ float lo2f(u32 v) { return __uint_as_float(v << 16); }
__device__ __forceinline__ float hi2f(u32 v) { return __uint_as_float(v & 0xffff0000u); }
__device__ __forceinline__ u16 f2bf(float f) {
  u32 u = __float_as_uint(f);
  u32 r = (u + 0x7fffu + ((u >> 16) & 1u)) >> 16;
  return (u16)r;
}
__device__ __forceinline__ u32 pack2(float a, float b) {
  return (u32)f2bf(a) | ((u32)f2bf(b) << 16);
}
__device__ __forceinline__ float tfast(float x) {
  x = fminf(fmaxf(x, -15.f), 15.f);
  float e = __expf(2.f * x);
  return (e - 1.f) * __builtin_amdgcn_rcpf(e + 1.f);
}

__global__ void prep_kernel(const float* __restrict__ Wsa1, const float* __restrict__ Wdi1,
                            const float* __restrict__ Wei1, const float* __restrict__ Weei,
                            const float* __restrict__ We0, const float* __restrict__ We1,
                            float* __restrict__ ws) {
  const int t = blockIdx.x * blockDim.x + threadIdx.x;
  const int T = gridDim.x * blockDim.x;
  const float* srcs[6] = {Wsa1, Wdi1, Wei1, Weei, We0, We1};
#pragma unroll 1
  for (int m = 0; m < 6; ++m)
    for (int i = t; i < 4096; i += T) {
      const int c = i >> 6, j = i & 63;
      ws[m * 4096 + i] = srcs[m][j * 64 + c];   // wsT[c][j] = W[j][c]
    }
}

// s_ion = tanh(feat_ion @ Ws_ei + bs_ei)  [4][64], batch-independent; + feat_ion passthrough
__global__ void sion_kernel(const float* __restrict__ fion, const float* __restrict__ Wsei,
                            const float* __restrict__ bsei, float* __restrict__ ws,
                            float* __restrict__ out) {
  const int t = threadIdx.x;
  if (t < 128) out[OUT_ION + t] = fion[t];
  const int i = t >> 6, c = t & 63;
  float acc = bsei[c];
  for (int k = 0; k < 32; ++k)
    acc += fion[i * 32 + k] * Wsei[k * 64 + c];
  ws[OFF_SION + i * 64 + c] = tfast(acc);
}

struct GP {
  const float *fel, *fee, *fei, *dee, *dei;
  const float *Wsa0, *bsa0, *bsa1;
  const float *Wdi0, *bdi0, *bdi1;
  const float *Wei0, *bei0, *bei1;
  const float *Wuei, *buei, *beei;
  const float *Ws0, *bs0, *Wu0, *bu0, *be0;
  const float *Ws1, *bs1, *Wu1, *bu1, *be1;
  const float *ws;
  float *out;
};

__global__ __launch_bounds__(512, 2) void gnn_kernel(GP g) {
  const int b = blockIdx.x;
  const int t = threadIdx.x;
  const int wv = t >> 6, ln = t & 63;

  // bf16 pairs, row pitch 33 words (66 elems) -> lane-stride-33 is bank-conflict-free
  __shared__ u32 s_ee32[256 * 33];   // 33792 B  el-el edges [e][c] bf16-packed
  __shared__ u32 s_ei32[64 * 33];    //  8448 B  el-ion edges
  __shared__ float s_emb[16 * 128];  //  8192 B
  __shared__ float s_nd[16 * 64];    //  4096 B
  __shared__ float s_agg[16 * 64];   //  4096 B
  __shared__ float s_xel[16 * 32];   //  2048 B
  __shared__ float s_mee[256];       //  1024 B
  __shared__ float s_mei[64];        //   256 B

  // ---- P0: masks + feat_el staging ----
  if (t < 256) s_mee[t] = __expf(g.dee[b * 256 + t] * -0.2f);
  if (t < 64)  s_mei[t] = __expf(g.dei[b * 64 + t] * -0.2f);
  s_xel[t] = g.fel[b * 512 + t];   // 512 elems == blockDim
  __syncthreads();

  // ---- P1: edge MLPs (4->64->64, tanh both layers) ----
  {
    // el-el: quadrant q = wv>>1 (q0 up-up, q1 up-dn, q2 dn-up, q3 dn-dn); half h = wv&1 splits channels
    const int q = wv >> 1, h = wv & 1;
    const int i_el = ((q >> 1) << 3) + (ln >> 3);
    const int j_el = ((q & 1) << 3) + (ln & 7);
    const int e = i_el * 16 + j_el;
    const bool same = (q == 0) || (q == 3);
    const float* W0  = same ? g.Wsa0 : g.Wdi0;
    const float* b0  = same ? g.bsa0 : g.bdi0;
    const float* W1T = g.ws + (same ? OFF_Wsa1T : OFF_Wdi1T);
    const float* b1  = same ? g.bsa1 : g.bdi1;
    const float4 xv = *(const float4*)(g.fee + (size_t)(b * 256 + e) * 4);
    float h1[64];
#pragma unroll
    for (int c = 0; c < 64; ++c)
      h1[c] = tfast(b0[c] + xv.x * W0[c] + xv.y * W0[64 + c] + xv.z * W0[128 + c] + xv.w * W0[192 + c]);
#pragma unroll 1
    for (int cp = 0; cp < 16; ++cp) {
      const int c = h * 32 + cp * 2;
      float a0 = b1[c], a1 = b1[c + 1];
      const float* w0 = W1T + c * 64;
      const float* w1 = w0 + 64;
#pragma unroll
      for (int j = 0; j < 64; ++j) { a0 += h1[j] * w0[j]; a1 += h1[j] * w1[j]; }
      s_ee32[e * 33 + (c >> 1)] = pack2(tfast(a0), tfast(a1));
    }
  }
  {
    // el-ion: 64 edges, lane = edge; each of 8 waves does 8 channels (layer1 redundant per wave)
    const float4 xv = *(const float4*)(g.fei + (size_t)(b * 64 + ln) * 4);
    const float* W0  = g.Wei0;
    const float* b0  = g.bei0;
    const float* W1T = g.ws + OFF_Wei1T;
    const float* b1  = g.bei1;
    float h1[64];
#pragma unroll
    for (int c = 0; c < 64; ++c)
      h1[c] = tfast(b0[c] + xv.x * W0[c] + xv.y * W0[64 + c] + xv.z * W0[128 + c] + xv.w * W0[192 + c]);
#pragma unroll 1
    for (int cp = 0; cp < 4; ++cp) {
      const int c = wv * 8 + cp * 2;
      float a0 = b1[c], a1 = b1[c + 1];
      const float* w0 = W1T + c * 64;
      const float* w1 = w0 + 64;
#pragma unroll
      for (int j = 0; j < 64; ++j) { a0 += h1[j] * w0[j]; a1 += h1[j] * w1[j]; }
      s_ei32[ln * 33 + (c >> 1)] = pack2(tfast(a0), tfast(a1));
    }
  }
  __syncthreads();

  // ---- P2a: el-ion aggregation: agg[r][c] = sum_i e[r][i][c] * s_ion[i][c] * mask[r][i] ----
  {
    const int c = t & 63, rr = t >> 6;
    const float* sion = g.ws + OFF_SION;
    const int wIdx = c >> 1;
    const bool hi = c & 1;
#pragma unroll
    for (int rh = 0; rh < 2; ++rh) {
      const int r = rr + rh * 8;
      float a = 0.f;
#pragma unroll
      for (int i = 0; i < 4; ++i) {
        const u32 v = s_ei32[(r * 4 + i) * 33 + wIdx];
        a += (hi ? hi2f(v) : lo2f(v)) * sion[i * 64 + c] * s_mei[r * 4 + i];
      }
      s_agg[r * 64 + c] = a;
    }
  }
  __syncthreads();

  // ---- P2b: node update from [feat_el(32), agg(64)] @ Wu_ei(96x128) ----
  {
    const int d = t & 127, gi = t >> 7;
    const float* Wu = g.Wuei;
    float acc[4];
#pragma unroll
    for (int r2 = 0; r2 < 4; ++r2) acc[r2] = g.buei[d];
#pragma unroll 1
    for (int k = 0; k < 32; ++k) {
      const float wk = Wu[k * 128 + d];
#pragma unroll
      for (int r2 = 0; r2 < 4; ++r2) acc[r2] += s_xel[(gi * 4 + r2) * 32 + k] * wk;
    }
#pragma unroll 1
    for (int k = 0; k < 64; ++k) {
      const float wk = Wu[(32 + k) * 128 + d];
#pragma unroll
      for (int r2 = 0; r2 < 4; ++r2) acc[r2] += s_agg[(gi * 4 + r2) * 64 + k] * wk;
    }
#pragma unroll
    for (int r2 = 0; r2 < 4; ++r2) s_emb[(gi * 4 + r2) * 128 + d] = tfast(acc[r2]);
  }

  // ---- P2c: el-ion edge update: tanh(e @ We_ei + be) ----
  {
    float x[64];
    const u32* row = s_ei32 + ln * 33;
#pragma unroll
    for (int jw = 0; jw < 32; ++jw) { const u32 v = row[jw]; x[2 * jw] = lo2f(v); x[2 * jw + 1] = hi2f(v); }
    __syncthreads();   // all rows read before any write
#pragma unroll 1
    for (int cp = 0; cp < 4; ++cp) {
      const int c = wv * 8 + cp * 2;
      float a0 = g.beei[c], a1 = g.beei[c + 1];
      const float* w0 = g.ws + OFF_WeeiT + c * 64;
      const float* w1 = w0 + 64;
#pragma unroll
      for (int j = 0; j < 64; ++j) { a0 += x[j] * w0[j]; a1 += x[j] * w1[j]; }
      s_ei32[ln * 33 + (c >> 1)] = pack2(tfast(a0), tfast(a1));
    }
  }
  __syncthreads();

  // ---- P2d: unpack updated el-ion edges to f32 out (coalesced float2) ----
  {
    float2* o = (float2*)(g.out + OUT_EI + (size_t)b * 4096);
#pragma unroll
    for (int ii = 0; ii < 4; ++ii) {
      const int iw = ii * 512 + t;           // [0,2048): e = iw>>5, word = iw&31 -> floats 2*iw, 2*iw+1
      const u32 v = s_ei32[(iw >> 5) * 33 + (iw & 31)];
      o[iw] = make_float2(lo2f(v), hi2f(v));
    }
  }
  __syncthreads();

  // ---- P3/P4: two dense el-el GNN iterations ----
#pragma unroll 1
  for (int it = 0; it < 2; ++it) {
    const float* Ws  = it ? g.Ws1 : g.Ws0;
    const float* bs  = it ? g.bs1 : g.bs0;
    const float* Wu  = it ? g.Wu1 : g.Wu0;
    const float* bu  = it ? g.bu1 : g.bu0;
    const float* WeT = g.ws + (it ? OFF_We1T : OFF_We0T);
    const float* be  = it ? g.be1 : g.be0;

    // a) sender projection s_nd = tanh(emb @ Ws + bs)
    {
      const int c = t & 63, w8 = t >> 6;
      float a0 = bs[c], a1 = bs[c];
#pragma unroll 1
      for (int k = 0; k < 128; ++k) {
        const float wk = Ws[k * 64 + c];
        a0 += s_emb[w8 * 128 + k] * wk;
        a1 += s_emb[(w8 + 8) * 128 + k] * wk;
      }
      s_nd[w8 * 64 + c] = tfast(a0);
      s_nd[(w8 + 8) * 64 + c] = tfast(a1);
    }
    __syncthreads();

    // b) masked aggregation over senders
    {
      const int c = t & 63, rr = t >> 6;
      const int wIdx = c >> 1;
      const bool hi = c & 1;
#pragma unroll
      for (int rh = 0; rh < 2; ++rh) {
        const int r = rr + rh * 8;
        float a = 0.f;
#pragma unroll
        for (int s = 0; s < 16; ++s) {
          const u32 v = s_ee32[(r * 16 + s) * 33 + wIdx];
          a += (hi ? hi2f(v) : lo2f(v)) * s_nd[s * 64 + c] * s_mee[r * 16 + s];
        }
        s_agg[r * 64 + c] = a;
      }
    }
    __syncthreads();

    // c) node update from [emb(128), agg(64)] @ Wu(192x128)
    {
      const int d = t & 127, gi = t >> 7;
      float acc[4];
#pragma unroll
      for (int r2 = 0; r2 < 4; ++r2) acc[r2] = bu[d];
#pragma unroll 1
      for (int k = 0; k < 128; ++k) {
        const float wk = Wu[k * 128 + d];
#pragma unroll
        for (int r2 = 0; r2 < 4; ++r2) acc[r2] += s_emb[(gi * 4 + r2) * 128 + k] * wk;
      }
#pragma unroll 1
      for (int k = 0; k < 64; ++k) {
        const float wk = Wu[(128 + k) * 128 + d];
#pragma unroll
        for (int r2 = 0; r2 < 4; ++r2) acc[r2] += s_agg[(gi * 4 + r2) * 64 + k] * wk;
      }
      __syncthreads();   // all reads of old emb complete
#pragma unroll
      for (int r2 = 0; r2 < 4; ++r2) {
        const float v = tfast(acc[r2]);
        s_emb[(gi * 4 + r2) * 128 + d] = v;
        if (it == 1) g.out[OUT_EMB + (size_t)b * 2048 + (gi * 4 + r2) * 128 + d] = v;
      }
    }
    __syncthreads();

    // d) edge update: tanh(e @ We + be); each thread owns one edge row, half the channels
    {
      const int e = t & 255, hh = t >> 8;
      float x[64];
      const u32* row = s_ee32 + e * 33;
#pragma unroll
      for (int jw = 0; jw < 32; ++jw) { const u32 v = row[jw]; x[2 * jw] = lo2f(v); x[2 * jw + 1] = hi2f(v); }
      __syncthreads();   // all rows read before any write
#pragma unroll 1
      for (int cp = 0; cp < 16; ++cp) {
        const int c = hh * 32 + cp * 2;
        float a0 = be[c], a1 = be[c + 1];
        const float* w0 = WeT + c * 64;
        const float* w1 = w0 + 64;
#pragma unroll
        for (int j = 0; j < 64; ++j) { a0 += x[j] * w0[j]; a1 += x[j] * w1[j]; }
        s_ee32[e * 33 + (c >> 1)] = pack2(tfast(a0), tfast(a1));
      }
    }
    __syncthreads();
  }

  // ---- final: unpack el-el edges to f32 out (coalesced float2) ----
  {
    float2* o = (float2*)(g.out + OUT_EE + (size_t)b * 16384);
#pragma unroll 1
    for (int ii = 0; ii < 16; ++ii) {
      const int iw = ii * 512 + t;           // [0,8192): e = iw>>5, word = iw&31
      const u32 v = s_ee32[(iw >> 5) * 33 + (iw & 31)];
      o[iw] = make_float2(lo2f(v), hi2f(v));
    }
  }
}

extern "C" void kernel_launch(void* const* d_in, const int* in_sizes, int n_in,
                              void* d_out, int out_size, void* d_ws, size_t ws_size,
                              hipStream_t stream) {
  (void)in_sizes; (void)n_in; (void)out_size; (void)ws_size;
  GP g;
  g.fel  = (const float*)d_in[0];
  g.fee  = (const float*)d_in[1];
  g.fei  = (const float*)d_in[2];
  const float* fion = (const float*)d_in[3];
  g.dee  = (const float*)d_in[5];
  g.dei  = (const float*)d_in[6];

  g.Wei0 = (const float*)d_in[7];  g.bei0 = (const float*)d_in[8];
  const float* Wei1 = (const float*)d_in[9];  g.bei1 = (const float*)d_in[10];
  g.Wsa0 = (const float*)d_in[11]; g.bsa0 = (const float*)d_in[12];
  const float* Wsa1 = (const float*)d_in[13]; g.bsa1 = (const float*)d_in[14];
  g.Wdi0 = (const float*)d_in[15]; g.bdi0 = (const float*)d_in[16];
  const float* Wdi1 = (const float*)d_in[17]; g.bdi1 = (const float*)d_in[18];
  // d_in[19..22] = ion-ion MLP weights: unused (output _edge_ion_ion is dropped)
  const float* Wsei = (const float*)d_in[23];
  const float* bsei = (const float*)d_in[24];
  g.Wuei = (const float*)d_in[25]; g.buei = (const float*)d_in[26];
  const float* Weei = (const float*)d_in[27]; g.beei = (const float*)d_in[28];
  g.Ws0  = (const float*)d_in[29]; g.bs0  = (const float*)d_in[30];
  g.Wu0  = (const float*)d_in[31]; g.bu0  = (const float*)d_in[32];
  const float* We0 = (const float*)d_in[33]; g.be0  = (const float*)d_in[34];
  g.Ws1  = (const float*)d_in[35]; g.bs1  = (const float*)d_in[36];
  g.Wu1  = (const float*)d_in[37]; g.bu1  = (const float*)d_in[38];
  const float* We1 = (const float*)d_in[39]; g.be1  = (const float*)d_in[40];

  float* wsf = (float*)d_ws;
  g.ws = wsf;
  g.out = (float*)d_out;

  hipLaunchKernelGGL(prep_kernel, dim3(16), dim3(256), 0, stream,
                     Wsa1, Wdi1, Wei1, Weei, We0, We1, wsf);
  hipLaunchKernelGGL(sion_kernel, dim3(1), dim3(256), 0, stream,
                     fion, Wsei, bsei, wsf, g.out);
  hipLaunchKernelGGL(gnn_kernel, dim3(2048), dim3(512), 0, stream, g);
}

// Round 3
// 2145.277 us; speedup vs baseline: 1.0731x; 1.0731x over previous
//
#include <hip/hip_runtime.h>

typedef unsigned short u16;
typedef unsigned int u32;

// d_ws layout (floats): six transposed 64x64 matrices + s_ion
#define OFF_Wsa1T  0
#define OFF_Wdi1T  4096
#define OFF_Wei1T  8192
#define OFF_WeeiT  12288
#define OFF_We0T   16384
#define OFF_We1T   20480
#define OFF_SION   24576
// total 24832 floats

// d_out layout (float elements):
#define OUT_EMB 0
#define OUT_ION 4194304
#define OUT_EE  4194432
#define OUT_EI  37748864

__device__ __forceinline__ float lo2f(u32 v) { return __uint_as_float(v << 16); }
__device__ __forceinline__ float hi2f(u32 v) { return __uint_as_float(v & 0xffff0000u); }
__device__ __forceinline__ u16 f2bf(float f) {
  u32 u = __float_as_uint(f);
  u32 r = (u + 0x7fffu + ((u >> 16) & 1u)) >> 16;
  return (u16)r;
}
__device__ __forceinline__ u32 pack2(float a, float b) {
  return (u32)f2bf(a) | ((u32)f2bf(b) << 16);
}
__device__ __forceinline__ float tfast(float x) {
  x = fminf(fmaxf(x, -15.f), 15.f);
  float e = __expf(2.f * x);
  return (e - 1.f) * __builtin_amdgcn_rcpf(e + 1.f);
}

__global__ void prep_kernel(const float* __restrict__ Wsa1, const float* __restrict__ Wdi1,
                            const float* __restrict__ Wei1, const float* __restrict__ Weei,
                            const float* __restrict__ We0, const float* __restrict__ We1,
                            float* __restrict__ ws) {
  const int t = blockIdx.x * blockDim.x + threadIdx.x;
  const int T = gridDim.x * blockDim.x;
  const float* srcs[6] = {Wsa1, Wdi1, Wei1, Weei, We0, We1};
#pragma unroll 1
  for (int m = 0; m < 6; ++m)
    for (int i = t; i < 4096; i += T) {
      const int c = i >> 6, j = i & 63;
      ws[m * 4096 + i] = srcs[m][j * 64 + c];   // wsT[c][j] = W[j][c]
    }
}

// s_ion = tanh(feat_ion @ Ws_ei + bs_ei)  [4][64], batch-independent; + feat_ion passthrough
__global__ void sion_kernel(const float* __restrict__ fion, const float* __restrict__ Wsei,
                            const float* __restrict__ bsei, float* __restrict__ ws,
                            float* __restrict__ out) {
  const int t = threadIdx.x;
  if (t < 128) out[OUT_ION + t] = fion[t];
  const int i = t >> 6, c = t & 63;
  float acc = bsei[c];
  for (int k = 0; k < 32; ++k)
    acc += fion[i * 32 + k] * Wsei[k * 64 + c];
  ws[OFF_SION + i * 64 + c] = tfast(acc);
}

struct GP {
  const float *__restrict__ fel; const float *__restrict__ fee; const float *__restrict__ fei;
  const float *__restrict__ dee; const float *__restrict__ dei;
  const float *__restrict__ Wsa0; const float *__restrict__ bsa0; const float *__restrict__ bsa1;
  const float *__restrict__ Wdi0; const float *__restrict__ bdi0; const float *__restrict__ bdi1;
  const float *__restrict__ Wei0; const float *__restrict__ bei0; const float *__restrict__ bei1;
  const float *__restrict__ Wuei; const float *__restrict__ buei; const float *__restrict__ beei;
  const float *__restrict__ Ws0; const float *__restrict__ bs0; const float *__restrict__ Wu0;
  const float *__restrict__ bu0; const float *__restrict__ be0;
  const float *__restrict__ Ws1; const float *__restrict__ bs1; const float *__restrict__ Wu1;
  const float *__restrict__ bu1; const float *__restrict__ be1;
  const float *__restrict__ ws;
  float *__restrict__ out;
};

__global__ __launch_bounds__(512, 2) void gnn_kernel(GP g) {
  const int b = blockIdx.x;
  const int t = threadIdx.x;
  const int ln = t & 63;
  // wave-uniform indices forced into SGPRs so weight reads become s_load (scalar cache),
  // not per-lane global_load — this is the whole round-2 fix.
  const int wvu = __builtin_amdgcn_readfirstlane(t >> 6);
  const int hhu = __builtin_amdgcn_readfirstlane(t >> 8);

  // bf16 pairs, row pitch 33 words (66 elems) -> lane-stride-33 is bank-conflict-free
  __shared__ u32 s_ee32[256 * 33];   // 33792 B  el-el edges [e][c] bf16-packed
  __shared__ u32 s_ei32[64 * 33];    //  8448 B  el-ion edges
  __shared__ float s_emb[16 * 128];  //  8192 B
  __shared__ float s_nd[16 * 64];    //  4096 B
  __shared__ float s_agg[16 * 64];   //  4096 B
  __shared__ float s_xel[16 * 32];   //  2048 B
  __shared__ float s_mee[256];       //  1024 B
  __shared__ float s_mei[64];        //   256 B

  // ---- P0: masks + feat_el staging ----
  if (t < 256) s_mee[t] = __expf(g.dee[b * 256 + t] * -0.2f);
  if (t < 64)  s_mei[t] = __expf(g.dei[b * 64 + t] * -0.2f);
  s_xel[t] = g.fel[b * 512 + t];   // 512 elems == blockDim
  __syncthreads();

  // ---- P1: edge MLPs (4->64->64, tanh both layers) ----
  {
    // el-el: quadrant q (q0 up-up, q1 up-dn, q2 dn-up, q3 dn-dn); half h splits channels
    const int q = wvu >> 1, h = wvu & 1;
    const int i_el = ((q >> 1) << 3) + (ln >> 3);
    const int j_el = ((q & 1) << 3) + (ln & 7);
    const int e = i_el * 16 + j_el;
    const bool same = (q == 0) || (q == 3);
    const float* __restrict__ W0  = same ? g.Wsa0 : g.Wdi0;
    const float* __restrict__ b0  = same ? g.bsa0 : g.bdi0;
    const float* __restrict__ W1T = g.ws + (same ? OFF_Wsa1T : OFF_Wdi1T);
    const float* __restrict__ b1  = same ? g.bsa1 : g.bdi1;
    const float4 xv = *(const float4*)(g.fee + (size_t)(b * 256 + e) * 4);
    float h1[64];
#pragma unroll
    for (int c = 0; c < 64; ++c)
      h1[c] = tfast(b0[c] + xv.x * W0[c] + xv.y * W0[64 + c] + xv.z * W0[128 + c] + xv.w * W0[192 + c]);
#pragma unroll 1
    for (int cp = 0; cp < 16; ++cp) {
      const int c = h * 32 + cp * 2;
      float a0 = b1[c], a1 = b1[c + 1];
      const float* __restrict__ w0 = W1T + c * 64;
      const float* __restrict__ w1 = w0 + 64;
#pragma unroll
      for (int j = 0; j < 64; ++j) { a0 += h1[j] * w0[j]; a1 += h1[j] * w1[j]; }
      s_ee32[e * 33 + (c >> 1)] = pack2(tfast(a0), tfast(a1));
    }
  }
  {
    // el-ion: 64 edges, lane = edge; each of 8 waves does 8 channels (layer1 redundant per wave)
    const float4 xv = *(const float4*)(g.fei + (size_t)(b * 64 + ln) * 4);
    const float* __restrict__ W0  = g.Wei0;
    const float* __restrict__ b0  = g.bei0;
    const float* __restrict__ W1T = g.ws + OFF_Wei1T;
    const float* __restrict__ b1  = g.bei1;
    float h1[64];
#pragma unroll
    for (int c = 0; c < 64; ++c)
      h1[c] = tfast(b0[c] + xv.x * W0[c] + xv.y * W0[64 + c] + xv.z * W0[128 + c] + xv.w * W0[192 + c]);
#pragma unroll 1
    for (int cp = 0; cp < 4; ++cp) {
      const int c = wvu * 8 + cp * 2;
      float a0 = b1[c], a1 = b1[c + 1];
      const float* __restrict__ w0 = W1T + c * 64;
      const float* __restrict__ w1 = w0 + 64;
#pragma unroll
      for (int j = 0; j < 64; ++j) { a0 += h1[j] * w0[j]; a1 += h1[j] * w1[j]; }
      s_ei32[ln * 33 + (c >> 1)] = pack2(tfast(a0), tfast(a1));
    }
  }
  __syncthreads();

  // ---- P2a: el-ion aggregation: agg[r][c] = sum_i e[r][i][c] * s_ion[i][c] * mask[r][i] ----
  {
    const int c = t & 63, rr = t >> 6;
    const float* __restrict__ sion = g.ws + OFF_SION;
    const int wIdx = c >> 1;
    const bool hi = c & 1;
#pragma unroll
    for (int rh = 0; rh < 2; ++rh) {
      const int r = rr + rh * 8;
      float a = 0.f;
#pragma unroll
      for (int i = 0; i < 4; ++i) {
        const u32 v = s_ei32[(r * 4 + i) * 33 + wIdx];
        a += (hi ? hi2f(v) : lo2f(v)) * sion[i * 64 + c] * s_mei[r * 4 + i];
      }
      s_agg[r * 64 + c] = a;
    }
  }
  __syncthreads();

  // ---- P2b: node update from [feat_el(32), agg(64)] @ Wu_ei(96x128) ----
  {
    const int d = t & 127, gi = t >> 7;
    const float* __restrict__ Wu = g.Wuei;
    float acc[4];
#pragma unroll
    for (int r2 = 0; r2 < 4; ++r2) acc[r2] = g.buei[d];
#pragma unroll 1
    for (int k = 0; k < 32; ++k) {
      const float wk = Wu[k * 128 + d];
#pragma unroll
      for (int r2 = 0; r2 < 4; ++r2) acc[r2] += s_xel[(gi * 4 + r2) * 32 + k] * wk;
    }
#pragma unroll 1
    for (int k = 0; k < 64; ++k) {
      const float wk = Wu[(32 + k) * 128 + d];
#pragma unroll
      for (int r2 = 0; r2 < 4; ++r2) acc[r2] += s_agg[(gi * 4 + r2) * 64 + k] * wk;
    }
#pragma unroll
    for (int r2 = 0; r2 < 4; ++r2) s_emb[(gi * 4 + r2) * 128 + d] = tfast(acc[r2]);
  }

  // ---- P2c: el-ion edge update: tanh(e @ We_ei + be) ----
  {
    float x[64];
    const u32* row = s_ei32 + ln * 33;
#pragma unroll
    for (int jw = 0; jw < 32; ++jw) { const u32 v = row[jw]; x[2 * jw] = lo2f(v); x[2 * jw + 1] = hi2f(v); }
    __syncthreads();   // all rows read before any write
#pragma unroll 1
    for (int cp = 0; cp < 4; ++cp) {
      const int c = wvu * 8 + cp * 2;
      float a0 = g.beei[c], a1 = g.beei[c + 1];
      const float* __restrict__ w0 = g.ws + OFF_WeeiT + c * 64;
      const float* __restrict__ w1 = w0 + 64;
#pragma unroll
      for (int j = 0; j < 64; ++j) { a0 += x[j] * w0[j]; a1 += x[j] * w1[j]; }
      s_ei32[ln * 33 + (c >> 1)] = pack2(tfast(a0), tfast(a1));
    }
  }
  __syncthreads();

  // ---- P2d: unpack updated el-ion edges to f32 out (coalesced float2) ----
  {
    float2* o = (float2*)(g.out + OUT_EI + (size_t)b * 4096);
#pragma unroll
    for (int ii = 0; ii < 4; ++ii) {
      const int iw = ii * 512 + t;           // [0,2048): e = iw>>5, word = iw&31
      const u32 v = s_ei32[(iw >> 5) * 33 + (iw & 31)];
      o[iw] = make_float2(lo2f(v), hi2f(v));
    }
  }
  __syncthreads();

  // ---- P3/P4: two dense el-el GNN iterations ----
#pragma unroll 1
  for (int it = 0; it < 2; ++it) {
    const float* __restrict__ Ws  = it ? g.Ws1 : g.Ws0;
    const float* __restrict__ bs  = it ? g.bs1 : g.bs0;
    const float* __restrict__ Wu  = it ? g.Wu1 : g.Wu0;
    const float* __restrict__ bu  = it ? g.bu1 : g.bu0;
    const float* __restrict__ WeT = g.ws + (it ? OFF_We1T : OFF_We0T);
    const float* __restrict__ be  = it ? g.be1 : g.be0;

    // a) sender projection s_nd = tanh(emb @ Ws + bs)
    {
      const int c = t & 63, w8 = t >> 6;
      float a0 = bs[c], a1 = bs[c];
#pragma unroll 1
      for (int k = 0; k < 128; ++k) {
        const float wk = Ws[k * 64 + c];
        a0 += s_emb[w8 * 128 + k] * wk;
        a1 += s_emb[(w8 + 8) * 128 + k] * wk;
      }
      s_nd[w8 * 64 + c] = tfast(a0);
      s_nd[(w8 + 8) * 64 + c] = tfast(a1);
    }
    __syncthreads();

    // b) masked aggregation over senders
    {
      const int c = t & 63, rr = t >> 6;
      const int wIdx = c >> 1;
      const bool hi = c & 1;
#pragma unroll
      for (int rh = 0; rh < 2; ++rh) {
        const int r = rr + rh * 8;
        float a = 0.f;
#pragma unroll
        for (int s = 0; s < 16; ++s) {
          const u32 v = s_ee32[(r * 16 + s) * 33 + wIdx];
          a += (hi ? hi2f(v) : lo2f(v)) * s_nd[s * 64 + c] * s_mee[r * 16 + s];
        }
        s_agg[r * 64 + c] = a;
      }
    }
    __syncthreads();

    // c) node update from [emb(128), agg(64)] @ Wu(192x128)
    {
      const int d = t & 127, gi = t >> 7;
      float acc[4];
#pragma unroll
      for (int r2 = 0; r2 < 4; ++r2) acc[r2] = bu[d];
#pragma unroll 1
      for (int k = 0; k < 128; ++k) {
        const float wk = Wu[k * 128 + d];
#pragma unroll
        for (int r2 = 0; r2 < 4; ++r2) acc[r2] += s_emb[(gi * 4 + r2) * 128 + k] * wk;
      }
#pragma unroll 1
      for (int k = 0; k < 64; ++k) {
        const float wk = Wu[(128 + k) * 128 + d];
#pragma unroll
        for (int r2 = 0; r2 < 4; ++r2) acc[r2] += s_agg[(gi * 4 + r2) * 64 + k] * wk;
      }
      __syncthreads();   // all reads of old emb complete
#pragma unroll
      for (int r2 = 0; r2 < 4; ++r2) {
        const float v = tfast(acc[r2]);
        s_emb[(gi * 4 + r2) * 128 + d] = v;
        if (it == 1) g.out[OUT_EMB + (size_t)b * 2048 + (gi * 4 + r2) * 128 + d] = v;
      }
    }
    __syncthreads();

    // d) edge update: tanh(e @ We + be); each thread owns one edge row, half the channels
    {
      const int e = t & 255;
      float x[64];
      const u32* row = s_ee32 + e * 33;
#pragma unroll
      for (int jw = 0; jw < 32; ++jw) { const u32 v = row[jw]; x[2 * jw] = lo2f(v); x[2 * jw + 1] = hi2f(v); }
      __syncthreads();   // all rows read before any write
#pragma unroll 1
      for (int cp = 0; cp < 16; ++cp) {
        const int c = hhu * 32 + cp * 2;
        float a0 = be[c], a1 = be[c + 1];
        const float* __restrict__ w0 = WeT + c * 64;
        const float* __restrict__ w1 = w0 + 64;
#pragma unroll
        for (int j = 0; j < 64; ++j) { a0 += x[j] * w0[j]; a1 += x[j] * w1[j]; }
        s_ee32[e * 33 + (c >> 1)] = pack2(tfast(a0), tfast(a1));
      }
    }
    __syncthreads();
  }

  // ---- final: unpack el-el edges to f32 out (coalesced float2) ----
  {
    float2* o = (float2*)(g.out + OUT_EE + (size_t)b * 16384);
#pragma unroll 1
    for (int ii = 0; ii < 16; ++ii) {
      const int iw = ii * 512 + t;           // [0,8192): e = iw>>5, word = iw&31
      const u32 v = s_ee32[(iw >> 5) * 33 + (iw & 31)];
      o[iw] = make_float2(lo2f(v), hi2f(v));
    }
  }
}

extern "C" void kernel_launch(void* const* d_in, const int* in_sizes, int n_in,
                              void* d_out, int out_size, void* d_ws, size_t ws_size,
                              hipStream_t stream) {
  (void)in_sizes; (void)n_in; (void)out_size; (void)ws_size;
  GP g;
  g.fel  = (const float*)d_in[0];
  g.fee  = (const float*)d_in[1];
  g.fei  = (const float*)d_in[2];
  const float* fion = (const float*)d_in[3];
  g.dee  = (const float*)d_in[5];
  g.dei  = (const float*)d_in[6];

  g.Wei0 = (const float*)d_in[7];  g.bei0 = (const float*)d_in[8];
  const float* Wei1 = (const float*)d_in[9];  g.bei1 = (const float*)d_in[10];
  g.Wsa0 = (const float*)d_in[11]; g.bsa0 = (const float*)d_in[12];
  const float* Wsa1 = (const float*)d_in[13]; g.bsa1 = (const float*)d_in[14];
  g.Wdi0 = (const float*)d_in[15]; g.bdi0 = (const float*)d_in[16];
  const float* Wdi1 = (const float*)d_in[17]; g.bdi1 = (const float*)d_in[18];
  // d_in[19..22] = ion-ion MLP weights: unused (output _edge_ion_ion is dropped)
  const float* Wsei = (const float*)d_in[23];
  const float* bsei = (const float*)d_in[24];
  g.Wuei = (const float*)d_in[25]; g.buei = (const float*)d_in[26];
  const float* Weei = (const float*)d_in[27]; g.beei = (const float*)d_in[28];
  g.Ws0  = (const float*)d_in[29]; g.bs0  = (const float*)d_in[30];
  g.Wu0  = (const float*)d_in[31]; g.bu0  = (const float*)d_in[32];
  const float* We0 = (const float*)d_in[33]; g.be0  = (const float*)d_in[34];
  g.Ws1  = (const float*)d_in[35]; g.bs1  = (const float*)d_in[36];
  g.Wu1  = (const float*)d_in[37]; g.bu1  = (const float*)d_in[38];
  const float* We1 = (const float*)d_in[39]; g.be1  = (const float*)d_in[40];

  float* wsf = (float*)d_ws;
  g.ws = wsf;
  g.out = (float*)d_out;

  hipLaunchKernelGGL(prep_kernel, dim3(16), dim3(256), 0, stream,
                     Wsa1, Wdi1, Wei1, Weei, We0, We1, wsf);
  hipLaunchKernelGGL(sion_kernel, dim3(1), dim3(256), 0, stream,
                     fion, Wsei, bsei, wsf, g.out);
  hipLaunchKernelGGL(gnn_kernel, dim3(2048), dim3(512), 0, stream, g);
}